// Round 7
// baseline (252.465 us; speedup 1.0000x reference)
//
#include <hip/hip_runtime.h>
#include <math.h>

// excess[b,m] = K·T + SIGMA*e*(T^4 - Tenv^4) - (H+F);  out = mean(|excess|)
// K = 5-band stencil on a 13x13 grid; GLx = -K[1][2]; GR = e_diag[1];
// interface nodes {0,12,156,168} are identity rows with e=0.
//
// v11: STATIC double-buffered grid-stride pipeline. v10's rotate-copy
// pipeline was defeated by regalloc (VGPR=52 proves the two buffers were
// merged). Here the two buffers are separate named structs (A,B), the loop
// is unrolled by 2 with no copies, and loads are UNCONDITIONAL (clamped
// safe address when the slot is invalid) so the compiler cannot sink them.
// sched_barrier(0) pins each load stage above the following compute.
// grid=1352 -> exactly 8 iterations/thread at the bench size.
// Compute body = v7/v10's verified mask-table math (absmax 0.0).

#define SIGMA_F 5.67e-8f

constexpr int BLOCK = 256;

typedef float f4a __attribute__((ext_vector_type(4), aligned(4)));   // unaligned x4
typedef float f4b __attribute__((ext_vector_type(4), aligned(16)));  // aligned x4

struct Buf { f4b t0, t1, h0, h1, f0, f1; };

static __device__ __forceinline__ void loadbuf(
    Buf& b, const float* __restrict__ T, const float* __restrict__ H,
    const float* __restrict__ F, int e0, bool fast)
{
    const int e = fast ? e0 : 16;          // clamped, in-bounds, 16B-aligned
    b.t0 = *(const f4b*)(T + e);
    b.t1 = *(const f4b*)(T + e + 4);
    b.h0 = __builtin_nontemporal_load((const f4b*)(H + e));
    b.h1 = __builtin_nontemporal_load((const f4b*)(H + e + 4));
    b.f0 = __builtin_nontemporal_load((const f4b*)(F + e));
    b.f1 = __builtin_nontemporal_load((const f4b*)(F + e + 4));
}

static __device__ __forceinline__ float compute_fast(
    const Buf& b, int e0, int lane,
    const float* __restrict__ T, const float* __restrict__ Tenv,
    const unsigned* sTab, float GLx, float GRs)
{
    float acc = 0.0f;

    // South: value at local idx 8*lane + j - 13
    float sv[8];
    sv[0] = __shfl_up(b.t0.w, 2);
    sv[1] = __shfl_up(b.t1.x, 2);
    sv[2] = __shfl_up(b.t1.y, 2);
    sv[3] = __shfl_up(b.t1.z, 2);
    sv[4] = __shfl_up(b.t1.w, 2);
    sv[5] = __shfl_up(b.t0.x, 1);
    sv[6] = __shfl_up(b.t0.y, 1);
    sv[7] = __shfl_up(b.t0.z, 1);
    if (lane < 2) {                        // fringe below wave window
        f4a a = *(const f4a*)(T + e0 - 13);
        f4a c = *(const f4a*)(T + e0 - 9);
        sv[0] = a.x; sv[1] = a.y; sv[2] = a.z; sv[3] = a.w;
        sv[4] = c.x; sv[5] = c.y; sv[6] = c.z; sv[7] = c.w;
    }
    // North: value at local idx 8*lane + j + 13
    float nv[8];
    nv[0] = __shfl_down(b.t1.y, 1);
    nv[1] = __shfl_down(b.t1.z, 1);
    nv[2] = __shfl_down(b.t1.w, 1);
    nv[3] = __shfl_down(b.t0.x, 2);
    nv[4] = __shfl_down(b.t0.y, 2);
    nv[5] = __shfl_down(b.t0.z, 2);
    nv[6] = __shfl_down(b.t0.w, 2);
    nv[7] = __shfl_down(b.t1.x, 2);
    if (lane >= 62) {                      // fringe above wave window
        f4a a = *(const f4a*)(T + e0 + 13);
        f4a c = *(const f4a*)(T + e0 + 17);
        nv[0] = a.x; nv[1] = a.y; nv[2] = a.z; nv[3] = a.w;
        nv[4] = c.x; nv[5] = c.y; nv[6] = c.z; nv[7] = c.w;
    }
    // West / East chunk edges
    float left = __shfl_up(b.t1.w, 1);
    if (lane == 0) left = T[e0 - 1];
    float right = __shfl_down(b.t0.x, 1);
    if (lane == 63) right = T[e0 + 8];

    const unsigned ue = (unsigned)e0;
    const unsigned b0 = ue / 169u;         // magic-mul
    const int m0 = (int)(ue - b0 * 169u);

    float tvA = Tenv[b0];
    float tvB = tvA;
    if (m0 >= 162) tvB = Tenv[b0 + 1];     // 8-group crosses batch boundary
    const float tv4A = (tvA * tvA) * (tvA * tvA);
    const float tv4B = (tvB * tvB) * (tvB * tvB);

    const float tCv[8] = {b.t0.x, b.t0.y, b.t0.z, b.t0.w,
                          b.t1.x, b.t1.y, b.t1.z, b.t1.w};
    const float tWv[8] = {left, b.t0.x, b.t0.y, b.t0.z,
                          b.t0.w, b.t1.x, b.t1.y, b.t1.z};
    const float tEv[8] = {b.t0.y, b.t0.z, b.t0.w, b.t1.x,
                          b.t1.y, b.t1.z, b.t1.w, right};
    const float hq[8]  = {b.h0.x + b.f0.x, b.h0.y + b.f0.y,
                          b.h0.z + b.f0.z, b.h0.w + b.f0.w,
                          b.h1.x + b.f1.x, b.h1.y + b.f1.y,
                          b.h1.z + b.f1.z, b.h1.w + b.f1.w};

    #pragma unroll
    for (int j = 0; j < 8; ++j) {
        const unsigned w = sTab[m0 + j];            // padded table: no mod
        const float mW = (float)(w & 0xffu);        // v_cvt_f32_ubyte0..3
        const float mE = (float)((w >> 8) & 0xffu);
        const float mN = (float)((w >> 16) & 0xffu);
        const float mS = (float)(w >> 24);

        const float t = tCv[j];
        float s = mW * tWv[j];
        s = fmaf(mE, tEv[j], s);
        s = fmaf(mN, nv[j], s);
        s = fmaf(mS, sv[j], s);
        const float nn = (mW + mE) + (mN + mS);
        const float q  = hq[j];
        const float tv4 = (m0 + j >= 169) ? tv4B : tv4A;
        const float t2 = t * t;
        const float d  = fmaf(t2, t2, -tv4);        // t^4 - tv^4
        const float core = fmaf(GLx, fmaf(nn, t, -s), fmaf(GRs, d, -q));
        const float ex = (nn == 2.0f) ? (t - q) : core;  // interface = corner
        acc += fabsf(ex);
    }
    return acc;
}

static __device__ __forceinline__ float compute_slow(
    int e0, int total,
    const float* __restrict__ T, const float* __restrict__ H,
    const float* __restrict__ F, const float* __restrict__ Tenv,
    float GLx, float GRs)
{
    float acc = 0.0f;
    #pragma unroll
    for (int j = 0; j < 8; ++j) {
        int e = e0 + j;
        if (e >= total) break;
        unsigned bb = (unsigned)e / 169u;
        int m = e - (int)bb * 169;
        unsigned q13 = (unsigned)m / 13u;
        int ii = m - (int)q13 * 13;
        bool cE = (ii < 12), cW = (ii > 0), cN = (m < 156), cS = (m >= 13);
        bool ifc = (m == 0) | (m == 12) | (m == 156) | (m == 168);
        float t  = T[e];
        float tEv = cE ? T[e + 1]  : 0.0f;
        float tWv = cW ? T[e - 1]  : 0.0f;
        float tNv = cN ? T[e + 13] : 0.0f;
        float tSv = cS ? T[e - 13] : 0.0f;
        float s  = tEv + tWv + tNv + tSv;
        float nn = (float)((int)cE + (int)cW + (int)cN + (int)cS);
        float tv = Tenv[bb];
        float tv4 = (tv * tv) * (tv * tv);
        float t2 = t * t, t4 = t2 * t2;
        float qq = H[e] + F[e];
        float ex = ifc ? (t - qq)
                       : (GLx * (nn * t - s) + GRs * (t4 - tv4) - qq);
        acc += fabsf(ex);
    }
    return acc;
}

__global__ __launch_bounds__(256) void fused_residual_v11(
    const float* __restrict__ T,      // [B*169]
    const float* __restrict__ H,
    const float* __restrict__ F,
    const float* __restrict__ Tenv,   // [B]
    const float* __restrict__ K,      // [169*169]
    const float* __restrict__ Ediag,  // [169]
    float* __restrict__ partials,
    int total)
{
    __shared__ unsigned sTab[184];
    __shared__ float sred[BLOCK / 64];

    const float GLx = -K[1 * 169 + 2];     // interior coupling (dx==dy)
    const float GRs = SIGMA_F * Ediag[1];  // sigma * GR

    const int tid  = (int)threadIdx.x;
    const int lane = tid & 63;

    // per-m neighbor-mask table (736 B); padded so m0+j needs no mod
    if (tid < 184) {
        int m = (tid < 169) ? tid : tid - 169;
        int ii = m % 13;
        unsigned cW = (ii > 0)  ? 1u : 0u;
        unsigned cE = (ii < 12) ? 1u : 0u;
        unsigned cN = (m < 156) ? 1u : 0u;
        unsigned cS = (m >= 13) ? 1u : 0u;
        sTab[tid] = cW | (cE << 8) | (cN << 16) | (cS << 24);
    }
    __syncthreads();

    float acc = 0.0f;

    const int stride = (int)gridDim.x * BLOCK;

    // wave-uniform fast test: whole wave's 512-elem window + halo in bounds
    auto isfast = [&](int gg) -> bool {
        const int wb = gg * 8 - lane * 8;
        return (wb >= 16) && (wb + 64 * 8 + 16 <= total);
    };

    int  gA = (int)blockIdx.x * BLOCK + tid;
    bool vA = (gA * 8 < total);
    bool fA = vA && isfast(gA);

    Buf A, B;
    loadbuf(A, T, H, F, gA * 8, fA);
    __builtin_amdgcn_sched_barrier(0);

    while (vA) {
        const int  gB = gA + stride;
        const bool vB = (gB * 8 < total);
        const bool fB = vB && isfast(gB);

        loadbuf(B, T, H, F, gB * 8, fB);       // unconditional, clamped
        __builtin_amdgcn_sched_barrier(0);

        if (fA) acc += compute_fast(A, gA * 8, lane, T, Tenv, sTab, GLx, GRs);
        else    acc += compute_slow(gA * 8, total, T, H, F, Tenv, GLx, GRs);

        if (!vB) break;

        const int  gA2 = gB + stride;
        const bool vA2 = (gA2 * 8 < total);
        const bool fA2 = vA2 && isfast(gA2);

        loadbuf(A, T, H, F, gA2 * 8, fA2);     // unconditional, clamped
        __builtin_amdgcn_sched_barrier(0);

        if (fB) acc += compute_fast(B, gB * 8, lane, T, Tenv, sTab, GLx, GRs);
        else    acc += compute_slow(gB * 8, total, T, H, F, Tenv, GLx, GRs);

        gA = gA2; vA = vA2; fA = fA2;
    }

    #pragma unroll
    for (int off = 32; off > 0; off >>= 1)
        acc += __shfl_down(acc, off, 64);
    const int wid = tid >> 6;
    if (lane == 0) sred[wid] = acc;
    __syncthreads();
    if (tid == 0) {
        float s = 0.0f;
        #pragma unroll
        for (int w = 0; w < BLOCK / 64; ++w) s += sred[w];
        partials[blockIdx.x] = s;
    }
}

__global__ __launch_bounds__(256) void finalize_kernel(
    const float* __restrict__ partials, int n,
    float* __restrict__ out, float inv_total)
{
    __shared__ float sred[BLOCK / 64];
    float acc = 0.0f;
    for (int i = (int)threadIdx.x; i < n; i += BLOCK) acc += partials[i];
    #pragma unroll
    for (int off = 32; off > 0; off >>= 1)
        acc += __shfl_down(acc, off, 64);
    int lane = threadIdx.x & 63;
    int wid  = threadIdx.x >> 6;
    if (lane == 0) sred[wid] = acc;
    __syncthreads();
    if (threadIdx.x == 0) {
        float s = 0.0f;
        #pragma unroll
        for (int w = 0; w < BLOCK / 64; ++w) s += sred[w];
        out[0] = s * inv_total;
    }
}

extern "C" void kernel_launch(void* const* d_in, const int* in_sizes, int n_in,
                              void* d_out, int out_size, void* d_ws, size_t ws_size,
                              hipStream_t stream) {
    const float* T    = (const float*)d_in[0];
    const float* H    = (const float*)d_in[1];
    const float* F    = (const float*)d_in[2];
    const float* Tenv = (const float*)d_in[3];
    const float* K    = (const float*)d_in[4];
    const float* E    = (const float*)d_in[5];
    float* out      = (float*)d_out;
    float* partials = (float*)d_ws;

    const int total = in_sizes[0];                 // 131072 * 169

    // grid=1352: at the bench size every thread runs exactly 8 iterations
    // (total/8 = 2768896 = 1352*256*8), giving the pipeline real depth.
    int grid = 1352;
    const int work = (total / 8 + BLOCK - 1) / BLOCK;
    if (grid > work) grid = work > 0 ? work : 1;
    if ((size_t)grid * sizeof(float) > ws_size) grid = (int)(ws_size / sizeof(float));
    if (grid < 1) grid = 1;

    fused_residual_v11<<<grid, BLOCK, 0, stream>>>(T, H, F, Tenv, K, E, partials,
                                                   total);

    const float inv_total = 1.0f / (float)total;
    finalize_kernel<<<1, BLOCK, 0, stream>>>(partials, grid, out, inv_total);
}